// Round 3
// baseline (406.605 us; speedup 1.0000x reference)
//
#include <hip/hip_runtime.h>

#define NT 65536
#define DM 256
#define NE 32

typedef __attribute__((ext_vector_type(8))) short v8bf;
typedef __attribute__((ext_vector_type(4))) float v4f;

// ctrl block offsets (ints)
#define C_RISKY 0
#define C_TC1 1
#define C_TC2 2
#define C_HIST1 8
#define C_HIST2 40
#define C_CUR1 72
#define C_CUR2 104

__device__ __forceinline__ unsigned short f2bf(float f) {
  union { float f; unsigned u; } v; v.f = f;
  unsigned r = v.u + 0x7FFFu + ((v.u >> 16) & 1u);  // RNE
  return (unsigned short)(r >> 16);
}

// async 16B global->LDS copy; LDS dst must be wave-uniform, HW scatters lane*16
#define GLOAD_LDS16(g, l)                                                     \
  __builtin_amdgcn_global_load_lds(                                           \
      (const __attribute__((address_space(1))) unsigned int*)(g),             \
      (__attribute__((address_space(3))) unsigned int*)(l), 16, 0, 0)

// x (fp32) -> xbf (bf16), pure streaming
__global__ __launch_bounds__(256) void convert_kernel(const float* __restrict__ x,
                                                      unsigned short* __restrict__ xbf) {
  size_t i = (size_t)blockIdx.x * 256 + threadIdx.x;  // 16B output chunk id
  const float4* s = (const float4*)x + i * 2;
  float4 a = s[0], b = s[1];
  union { v8bf v; unsigned short u[8]; uint4 q; } p;
  p.u[0] = f2bf(a.x); p.u[1] = f2bf(a.y); p.u[2] = f2bf(a.z); p.u[3] = f2bf(a.w);
  p.u[4] = f2bf(b.x); p.u[5] = f2bf(b.y); p.u[6] = f2bf(b.z); p.u[7] = f2bf(b.w);
  *(uint4*)(xbf + i * 8) = p.q;
}

// Gate weights: fp32 wgn[k][64] (fixup) + bf16 B^T wgnb[col][k] (MFMA).
__global__ __launch_bounds__(256) void prep_w(const float* __restrict__ Wg,
                                              const float* __restrict__ Wn,
                                              float* __restrict__ wgn,
                                              unsigned short* __restrict__ wgnb) {
  int i = blockIdx.x * 256 + threadIdx.x;
  if (i < 256 * 64) {
    int k = i >> 6, c = i & 63;
    float v = (c < 32) ? Wg[k * 32 + c] : Wn[k * 32 + (c - 32)];
    wgn[i] = v;
    wgnb[c * 256 + k] = f2bf(v);
  }
}

// WeT[e][h][d] = bf16(We[e][d][h]) — K-contiguous B^T layout for MFMA B-frags.
__global__ __launch_bounds__(256) void prep_wet(const float* __restrict__ We,
                                                unsigned short* __restrict__ WeT) {
  __shared__ float t[32][33];
  int e = blockIdx.x;
  int d0 = (blockIdx.y >> 3) * 32, h0 = (blockIdx.y & 7) * 32;
  int tx = threadIdx.x & 31, ty = threadIdx.x >> 5;
  const float* src = We + ((size_t)e * 256 + d0) * 256 + h0;
#pragma unroll
  for (int r = 0; r < 4; ++r) t[ty + r * 8][tx] = src[(size_t)(ty + r * 8) * 256 + tx];
  __syncthreads();
  unsigned short* dst = WeT + ((size_t)e * 256 + h0) * 256 + d0;
#pragma unroll
  for (int r = 0; r < 4; ++r) dst[(size_t)(ty + r * 8) * 256 + tx] = f2bf(t[tx][ty + r * 8]);
}

// Gate v3: bf16 MFMA GEMM H=[xWg | xWn], async LDS staging + xor-swizzle.
// LDS chunk (row, kc) holds source chunk kc^(row&7); reads apply same xor.
__global__ __launch_bounds__(256) void gate_kernel(const float* __restrict__ x,
                                                   const unsigned short* __restrict__ xbf,
                                                   int use_xbf,
                                                   const unsigned short* __restrict__ wgnb,
                                                   const float* __restrict__ nvec,
                                                   int4* __restrict__ records,
                                                   int* __restrict__ risky,
                                                   int* __restrict__ ctrl) {
  __shared__ __align__(16) union {
    struct { short Al[128 * 64]; short Bl[64 * 64]; } t;
    float H[128 * 67];
  } sm;
  __shared__ float nvs[32];
  __shared__ int lh[64];
  int tid = threadIdx.x;
  if (tid < 64) lh[tid] = 0;
  if (tid < 32) nvs[tid] = nvec[tid];
  int t0 = blockIdx.x * 128;
  int lane = tid & 63, wid = tid >> 6;
  int wm = wid * 32;  // 2 m-tiles of 16 per wave
  int lm = lane & 15, lk8 = (lane >> 4) * 8;
  int r0 = tid >> 3, kc = tid & 7;
  int kcs = kc ^ (r0 & 7);  // xor-swizzled source chunk (same for all j: 32j%8==0)
  v4f acc[2][4];
  v4f zero = {0.f, 0.f, 0.f, 0.f};
#pragma unroll
  for (int mi = 0; mi < 2; ++mi)
#pragma unroll
    for (int ni = 0; ni < 4; ++ni) acc[mi][ni] = zero;
  for (int k0 = 0; k0 < 256; k0 += 64) {
    __syncthreads();
    if (use_xbf) {
#pragma unroll
      for (int j = 0; j < 4; ++j)  // A: 128 rows x 8 chunks
        GLOAD_LDS16(xbf + ((size_t)(t0 + r0 + 32 * j) * 256 + k0 + kcs * 8),
                    sm.t.Al + (size_t)(256 * j + (tid & 192)) * 8);
#pragma unroll
      for (int j = 0; j < 2; ++j)  // B: 64 cols x 8 chunks
        GLOAD_LDS16(wgnb + ((size_t)(r0 + 32 * j) * 256 + k0 + kcs * 8),
                    sm.t.Bl + (size_t)(256 * j + (tid & 192)) * 8);
    } else {
#pragma unroll
      for (int j = 0; j < 4; ++j) {
        const float4* s = (const float4*)(x + ((size_t)(t0 + r0 + 32 * j) * 256 + k0 + kcs * 8));
        float4 a = s[0], b = s[1];
        union { v8bf v; unsigned short u[8]; } p;
        p.u[0] = f2bf(a.x); p.u[1] = f2bf(a.y); p.u[2] = f2bf(a.z); p.u[3] = f2bf(a.w);
        p.u[4] = f2bf(b.x); p.u[5] = f2bf(b.y); p.u[6] = f2bf(b.z); p.u[7] = f2bf(b.w);
        *(v8bf*)(sm.t.Al + (size_t)(tid + 256 * j) * 8) = p.v;
      }
#pragma unroll
      for (int j = 0; j < 2; ++j) {
        uint4 w = *(const uint4*)(wgnb + ((size_t)(r0 + 32 * j) * 256 + k0 + kcs * 8));
        *(uint4*)(sm.t.Bl + (size_t)(tid + 256 * j) * 8) = w;
      }
    }
    __syncthreads();
#pragma unroll
    for (int ks = 0; ks < 64; ks += 32) {
      int c = (ks + lk8) >> 3;
      int cs = c ^ (lm & 7);
      v8bf af[2], bfr[4];
#pragma unroll
      for (int mi = 0; mi < 2; ++mi) {
        int r = wm + mi * 16 + lm;
        af[mi] = *(const v8bf*)(sm.t.Al + (size_t)(r * 8 + cs) * 8);
      }
#pragma unroll
      for (int ni = 0; ni < 4; ++ni) {
        int cr = ni * 16 + lm;
        bfr[ni] = *(const v8bf*)(sm.t.Bl + (size_t)(cr * 8 + cs) * 8);
      }
#pragma unroll
      for (int mi = 0; mi < 2; ++mi)
#pragma unroll
        for (int ni = 0; ni < 4; ++ni)
          acc[mi][ni] = __builtin_amdgcn_mfma_f32_16x16x32_bf16(af[mi], bfr[ni], acc[mi][ni], 0, 0, 0);
    }
  }
  __syncthreads();  // Al/Bl dead; reuse as H
  int cg = lane & 15, rg = lane >> 4;
#pragma unroll
  for (int mi = 0; mi < 2; ++mi)
#pragma unroll
    for (int r = 0; r < 4; ++r) {
      int row = wm + mi * 16 + rg * 4 + r;
#pragma unroll
      for (int ni = 0; ni < 4; ++ni) sm.H[row * 67 + ni * 16 + cg] = acc[mi][ni][r];
    }
  __syncthreads();
  if (tid < 128) {
    int t = t0 + tid;
    float v1 = -3e38f, v2 = -3e38f, v3 = -3e38f;
    int i1 = 0, i2 = 0;
#pragma unroll 4
    for (int e = 0; e < 32; ++e) {
      float g = sm.H[tid * 67 + e];
      float n = sm.H[tid * 67 + 32 + e];
      float sp = fmaxf(n, 0.f) + log1pf(expf(-fabsf(n)));
      float he = fmaf(nvs[e], sp, g);
      if (he > v1) { v3 = v2; v2 = v1; i2 = i1; v1 = he; i1 = e; }
      else if (he > v2) { v3 = v2; v2 = he; i2 = e; }
      else if (he > v3) v3 = he;
    }
    float w1v = 1.f / (1.f + expf(v2 - v1));
    float w2v = 1.f / (1.f + expf(v1 - v2));
    records[t] = make_int4(i1, i2, __float_as_int(w1v), __float_as_int(w2v));
    atomicAdd(&lh[i1], 1);
    atomicAdd(&lh[32 + i2], 1);
    if (v2 - v3 < 2e-2f) {  // ~10 sigma of bf16-GEMM error on the gap
      int p = atomicAdd(&ctrl[C_RISKY], 1);
      risky[p] = t;
    }
  }
  __syncthreads();
  if (tid < 32) atomicAdd(&ctrl[C_HIST1 + tid], lh[tid]);
  else if (tid < 64) atomicAdd(&ctrl[C_HIST2 + (tid - 32)], lh[tid]);
}

// fp64 recompute of gating for risky tokens; patches records + histograms.
__global__ __launch_bounds__(256) void fixup_kernel(const float* __restrict__ x,
                                                    const float* __restrict__ wgn,
                                                    const float* __restrict__ nvec,
                                                    int4* __restrict__ records,
                                                    const int* __restrict__ risky,
                                                    int* __restrict__ ctrl) {
  int cnt = ctrl[C_RISKY];
  int lane = threadIdx.x & 63, wid = threadIdx.x >> 6;
  for (int r = blockIdx.x * 4 + wid; r < cnt; r += gridDim.x * 4) {
    int t = __builtin_amdgcn_readfirstlane(risky[r]);
    const float* xr = x + (size_t)t * 256;
    double a0 = 0.0, a1 = 0.0, a2 = 0.0, a3 = 0.0;
    for (int k = 0; k < 256; k += 4) {
      float4 xv = *(const float4*)(xr + k);
      a0 = fma((double)xv.x, (double)wgn[(k + 0) * 64 + lane], a0);
      a1 = fma((double)xv.y, (double)wgn[(k + 1) * 64 + lane], a1);
      a2 = fma((double)xv.z, (double)wgn[(k + 2) * 64 + lane], a2);
      a3 = fma((double)xv.w, (double)wgn[(k + 3) * 64 + lane], a3);
    }
    double acc = (a0 + a1) + (a2 + a3);
    double sv = __shfl(acc, lane + 32);
    double H;
    if (lane < 32) {
      double sp = fmax(sv, 0.0) + log1p(exp(-fabs(sv)));
      H = acc + (double)nvec[lane] * sp;
    } else
      H = -1e300;
    double v = H; int idx = lane;
#pragma unroll
    for (int off = 32; off >= 1; off >>= 1) {
      double ov = __shfl_xor(v, off); int oi = __shfl_xor(idx, off);
      if (ov > v || (ov == v && oi < idx)) { v = ov; idx = oi; }
    }
    int i1 = idx; double v1 = v;
    v = (lane == i1) ? -1e300 : H; idx = lane;
#pragma unroll
    for (int off = 32; off >= 1; off >>= 1) {
      double ov = __shfl_xor(v, off); int oi = __shfl_xor(idx, off);
      if (ov > v || (ov == v && oi < idx)) { v = ov; idx = oi; }
    }
    int i2 = idx; double v2 = v;
    if (lane == 0) {
      float w1v = (float)(1.0 / (1.0 + exp(v2 - v1)));
      float w2v = (float)(1.0 / (1.0 + exp(v1 - v2)));
      int4 old = records[t];
      if (old.x != i1) { atomicSub(&ctrl[C_HIST1 + old.x], 1); atomicAdd(&ctrl[C_HIST1 + i1], 1); }
      if (old.y != i2) { atomicSub(&ctrl[C_HIST2 + old.y], 1); atomicAdd(&ctrl[C_HIST2 + i2], 1); }
      records[t] = make_int4(i1, i2, __float_as_int(w1v), __float_as_int(w2v));
    }
  }
}

// Segment offsets + per-tile work tables (BM=128 tiles per expert segment).
__global__ __launch_bounds__(64) void scan_kernel(int* __restrict__ ctrl,
                                                  int4* __restrict__ table1,
                                                  int4* __restrict__ table2) {
  __shared__ int so1[32], so2[32], tp1[32], tp2[32];
  int tid = threadIdx.x;
  if (tid == 0) {
    int o = 0, tp = 0;
    for (int e = 0; e < 32; ++e) {
      so1[e] = o; tp1[e] = tp;
      int c = ctrl[C_HIST1 + e];
      o += c; tp += (c + 127) >> 7;
    }
    ctrl[C_TC1] = tp;
    o = 0; tp = 0;
    for (int e = 0; e < 32; ++e) {
      so2[e] = o; tp2[e] = tp;
      int c = ctrl[C_HIST2 + e];
      o += c; tp += (c + 127) >> 7;
    }
    ctrl[C_TC2] = tp;
  }
  __syncthreads();
  if (tid < 32) {
    int e = tid;
    ctrl[C_CUR1 + e] = so1[e];
    int c = ctrl[C_HIST1 + e];
    int nt = (c + 127) >> 7;
    for (int m = 0; m < nt; ++m)
      table1[tp1[e] + m] = make_int4(e, so1[e] + m * 128, min(128, c - m * 128), 0);
  } else if (tid < 64) {
    int e = tid - 32;
    ctrl[C_CUR2 + e] = so2[e];
    int c = ctrl[C_HIST2 + e];
    int nt = (c + 127) >> 7;
    for (int m = 0; m < nt; ++m)
      table2[tp2[e] + m] = make_int4(e, so2[e] + m * 128, min(128, c - m * 128), 0);
  }
}

// Bucket tokens by expert (intra-block rank + block base).
__global__ __launch_bounds__(256) void scatter_kernel(const int4* __restrict__ records,
                                                      int* __restrict__ ctrl,
                                                      int* __restrict__ perm1, float* __restrict__ pw1,
                                                      int* __restrict__ perm2, float* __restrict__ pw2) {
  __shared__ int lh1[32], lh2[32], b1[32], b2[32];
  int tid = threadIdx.x;
  if (tid < 32) { lh1[tid] = 0; lh2[tid] = 0; }
  __syncthreads();
  int t = blockIdx.x * 256 + tid;
  int4 rec = records[t];
  int r1 = atomicAdd(&lh1[rec.x], 1);
  int r2 = atomicAdd(&lh2[rec.y], 1);
  __syncthreads();
  if (tid < 32) {
    b1[tid] = atomicAdd(&ctrl[C_CUR1 + tid], lh1[tid]);
    b2[tid] = atomicAdd(&ctrl[C_CUR2 + tid], lh2[tid]);
  }
  __syncthreads();
  int s1 = b1[rec.x] + r1; perm1[s1] = t; pw1[s1] = __int_as_float(rec.z);
  int s2 = b2[rec.y] + r2; perm2[s2] = t; pw2[s2] = __int_as_float(rec.w);
}

// Grouped GEMM: out[tok,:] (+)= w * (x[tok,:] @ We[e]) + w*be[e,:], bf16 MFMA.
// Async LDS staging + xor-swizzle; BM=128, BN=128, BK=64; wave-tile 64x64.
__global__ __launch_bounds__(256) void expert_kernel(const float* __restrict__ x,
                                                     const unsigned short* __restrict__ xbf,
                                                     int use_xbf,
                                                     const unsigned short* __restrict__ WeT,
                                                     const float* __restrict__ be,
                                                     const int* __restrict__ perm,
                                                     const float* __restrict__ pw,
                                                     const int4* __restrict__ table,
                                                     const int* __restrict__ tcp,
                                                     float* __restrict__ out,
                                                     int accumulate) {
  int nt = *tcp;
  if (blockIdx.x >= nt) return;
  int4 ent = table[blockIdx.x];
  int e = ent.x, sbase = ent.y, rows = ent.z;
  int n0 = blockIdx.y * 128;
  __shared__ __align__(16) short Al[128 * 64];
  __shared__ __align__(16) short Bl[128 * 64];
  int tid = threadIdx.x;
  int lane = tid & 63, wid = tid >> 6;
  int wm = (wid & 1) * 64, wn = (wid >> 1) * 64;
  int lm = lane & 15, lk8 = (lane >> 4) * 8;
  int r0 = tid >> 3, kc = tid & 7;
  int kcs = kc ^ (r0 & 7);  // xor-swizzled source chunk (same for all j)
  int tok[4];
#pragma unroll
  for (int j = 0; j < 4; ++j) tok[j] = perm[sbase + min(r0 + 32 * j, rows - 1)];
  v4f acc[4][4];
  v4f zero = {0.f, 0.f, 0.f, 0.f};
#pragma unroll
  for (int mi = 0; mi < 4; ++mi)
#pragma unroll
    for (int ni = 0; ni < 4; ++ni) acc[mi][ni] = zero;
  for (int k0 = 0; k0 < 256; k0 += 64) {
    __syncthreads();
    if (use_xbf) {
#pragma unroll
      for (int j = 0; j < 4; ++j)
        GLOAD_LDS16(xbf + ((size_t)tok[j] * 256 + k0 + kcs * 8),
                    Al + (size_t)(256 * j + (tid & 192)) * 8);
#pragma unroll
      for (int j = 0; j < 4; ++j)
        GLOAD_LDS16(WeT + (((size_t)e * 256 + n0 + r0 + 32 * j) * 256 + k0 + kcs * 8),
                    Bl + (size_t)(256 * j + (tid & 192)) * 8);
    } else {
#pragma unroll
      for (int j = 0; j < 4; ++j) {
        const float4* s = (const float4*)(x + ((size_t)tok[j] * 256 + k0 + kcs * 8));
        float4 a = s[0], b = s[1];
        union { v8bf v; unsigned short u[8]; } p;
        p.u[0] = f2bf(a.x); p.u[1] = f2bf(a.y); p.u[2] = f2bf(a.z); p.u[3] = f2bf(a.w);
        p.u[4] = f2bf(b.x); p.u[5] = f2bf(b.y); p.u[6] = f2bf(b.z); p.u[7] = f2bf(b.w);
        *(v8bf*)(Al + (size_t)(tid + 256 * j) * 8) = p.v;
      }
#pragma unroll
      for (int j = 0; j < 4; ++j) {
        uint4 w = *(const uint4*)(WeT + (((size_t)e * 256 + n0 + r0 + 32 * j) * 256 + k0 + kcs * 8));
        *(uint4*)(Bl + (size_t)(tid + 256 * j) * 8) = w;
      }
    }
    __syncthreads();
#pragma unroll
    for (int ks = 0; ks < 64; ks += 32) {
      int c = (ks + lk8) >> 3;
      int cs = c ^ (lm & 7);
      v8bf af[4], bfr[4];
#pragma unroll
      for (int mi = 0; mi < 4; ++mi) {
        int r = wm + mi * 16 + lm;
        af[mi] = *(const v8bf*)(Al + (size_t)(r * 8 + cs) * 8);
      }
#pragma unroll
      for (int ni = 0; ni < 4; ++ni) {
        int cr = wn + ni * 16 + lm;
        bfr[ni] = *(const v8bf*)(Bl + (size_t)(cr * 8 + cs) * 8);
      }
#pragma unroll
      for (int mi = 0; mi < 4; ++mi)
#pragma unroll
        for (int ni = 0; ni < 4; ++ni)
          acc[mi][ni] = __builtin_amdgcn_mfma_f32_16x16x32_bf16(af[mi], bfr[ni], acc[mi][ni], 0, 0, 0);
    }
  }
  int cg = lane & 15, rg = lane >> 4;
#pragma unroll
  for (int mi = 0; mi < 4; ++mi) {
#pragma unroll
    for (int r = 0; r < 4; ++r) {
      int srow = wm + mi * 16 + rg * 4 + r;
      if (srow < rows) {
        int slot = sbase + srow;
        int tokr = perm[slot];
        float w = pw[slot];
        size_t ob = (size_t)tokr * 256;
#pragma unroll
        for (int ni = 0; ni < 4; ++ni) {
          int c = n0 + wn + ni * 16 + cg;
          float v = acc[mi][ni][r] * w + w * be[e * 256 + c];
          if (accumulate) out[ob + c] += v;
          else out[ob + c] = v;
        }
      }
    }
  }
}

extern "C" void kernel_launch(void* const* d_in, const int* in_sizes, int n_in,
                              void* d_out, int out_size, void* d_ws, size_t ws_size,
                              hipStream_t stream) {
  const float* x = (const float*)d_in[0];
  const float* Wg = (const float*)d_in[1];
  const float* Wn = (const float*)d_in[2];
  const float* We = (const float*)d_in[3];
  const float* be = (const float*)d_in[4];
  const float* nvec = (const float*)d_in[5];
  float* out = (float*)d_out;
  char* ws = (char*)d_ws;
  size_t off = 0;
  auto alloc = [&](size_t bytes) -> void* {
    void* p = ws + off;
    off = (off + bytes + 255) & ~(size_t)255;
    return p;
  };
  int* ctrl = (int*)alloc(4096);
  int4* records = (int4*)alloc((size_t)NT * 16);
  int* risky = (int*)alloc((size_t)NT * 4);
  int* perm1 = (int*)alloc((size_t)NT * 4);
  float* pw1 = (float*)alloc((size_t)NT * 4);
  int* perm2 = (int*)alloc((size_t)NT * 4);
  float* pw2 = (float*)alloc((size_t)NT * 4);
  int4* table1 = (int4*)alloc(1024 * 16);
  int4* table2 = (int4*)alloc(1024 * 16);
  float* wgn = (float*)alloc(256 * 64 * 4);
  unsigned short* wgnb = (unsigned short*)alloc(64 * 256 * 2);
  unsigned short* WeT = (unsigned short*)alloc((size_t)NE * 256 * 256 * 2);
  unsigned short* xbf = nullptr;
  int use_xbf = 0;
  if (off + (size_t)NT * 256 * 2 <= ws_size) {
    xbf = (unsigned short*)alloc((size_t)NT * 256 * 2);
    use_xbf = 1;
  }

  hipMemsetAsync(ctrl, 0, 4096, stream);
  prep_w<<<64, 256, 0, stream>>>(Wg, Wn, wgn, wgnb);
  prep_wet<<<dim3(32, 64), 256, 0, stream>>>(We, WeT);
  if (use_xbf) convert_kernel<<<NT * DM / 8 / 256, 256, 0, stream>>>(x, xbf);
  gate_kernel<<<NT / 128, 256, 0, stream>>>(x, xbf, use_xbf, wgnb, nvec, records, risky, ctrl);
  fixup_kernel<<<256, 256, 0, stream>>>(x, wgn, nvec, records, risky, ctrl);
  scan_kernel<<<1, 64, 0, stream>>>(ctrl, table1, table2);
  scatter_kernel<<<NT / 256, 256, 0, stream>>>(records, ctrl, perm1, pw1, perm2, pw2);
  expert_kernel<<<dim3(544, 2), 256, 0, stream>>>(x, xbf, use_xbf, WeT, be, perm1, pw1, table1,
                                                  ctrl + C_TC1, out, 0);
  expert_kernel<<<dim3(544, 2), 256, 0, stream>>>(x, xbf, use_xbf, WeT, be, perm2, pw2, table2,
                                                  ctrl + C_TC2, out, 1);
}

// Round 4
// 368.738 us; speedup vs baseline: 1.1027x; 1.1027x over previous
//
#include <hip/hip_runtime.h>

#define NT 65536
#define DM 256
#define NE 32

typedef __attribute__((ext_vector_type(8))) short v8bf;
typedef __attribute__((ext_vector_type(4))) float v4f;

// ctrl block offsets (ints)
#define C_RISKY 0
#define C_TC1 1
#define C_TC2 2
#define C_HIST1 8
#define C_HIST2 40
#define C_CUR1 72
#define C_CUR2 104

__device__ __forceinline__ unsigned short f2bf(float f) {
  union { float f; unsigned u; } v; v.f = f;
  unsigned r = v.u + 0x7FFFu + ((v.u >> 16) & 1u);  // RNE
  return (unsigned short)(r >> 16);
}
__device__ __forceinline__ float bf2f(unsigned short b) {
  union { unsigned u; float f; } v; v.u = ((unsigned)b) << 16; return v.f;
}

// async 16B global->LDS copy; LDS dst must be wave-uniform, HW scatters lane*16
#define GLOAD_LDS16(g, l)                                                     \
  __builtin_amdgcn_global_load_lds(                                           \
      (const __attribute__((address_space(1))) unsigned int*)(g),             \
      (__attribute__((address_space(3))) unsigned int*)(l), 16, 0, 0)

// x (fp32) -> xbf (bf16), pure streaming
__global__ __launch_bounds__(256) void convert_kernel(const float* __restrict__ x,
                                                      unsigned short* __restrict__ xbf) {
  size_t i = (size_t)blockIdx.x * 256 + threadIdx.x;  // 16B output chunk id
  const float4* s = (const float4*)x + i * 2;
  float4 a = s[0], b = s[1];
  union { v8bf v; unsigned short u[8]; uint4 q; } p;
  p.u[0] = f2bf(a.x); p.u[1] = f2bf(a.y); p.u[2] = f2bf(a.z); p.u[3] = f2bf(a.w);
  p.u[4] = f2bf(b.x); p.u[5] = f2bf(b.y); p.u[6] = f2bf(b.z); p.u[7] = f2bf(b.w);
  *(uint4*)(xbf + i * 8) = p.q;
}

// Gate weights: fp32 wgn[k][64] (fixup) + bf16 B^T wgnb[col][k] (MFMA).
__global__ __launch_bounds__(256) void prep_w(const float* __restrict__ Wg,
                                              const float* __restrict__ Wn,
                                              float* __restrict__ wgn,
                                              unsigned short* __restrict__ wgnb) {
  int i = blockIdx.x * 256 + threadIdx.x;
  if (i < 256 * 64) {
    int k = i >> 6, c = i & 63;
    float v = (c < 32) ? Wg[k * 32 + c] : Wn[k * 32 + (c - 32)];
    wgn[i] = v;
    wgnb[c * 256 + k] = f2bf(v);
  }
}

// WeT[e][h][d] = bf16(We[e][d][h]) — K-contiguous B^T layout for MFMA B-frags.
__global__ __launch_bounds__(256) void prep_wet(const float* __restrict__ We,
                                                unsigned short* __restrict__ WeT) {
  __shared__ float t[32][33];
  int e = blockIdx.x;
  int d0 = (blockIdx.y >> 3) * 32, h0 = (blockIdx.y & 7) * 32;
  int tx = threadIdx.x & 31, ty = threadIdx.x >> 5;
  const float* src = We + ((size_t)e * 256 + d0) * 256 + h0;
#pragma unroll
  for (int r = 0; r < 4; ++r) t[ty + r * 8][tx] = src[(size_t)(ty + r * 8) * 256 + tx];
  __syncthreads();
  unsigned short* dst = WeT + ((size_t)e * 256 + h0) * 256 + d0;
#pragma unroll
  for (int r = 0; r < 4; ++r) dst[(size_t)(ty + r * 8) * 256 + tx] = f2bf(t[tx][ty + r * 8]);
}

// Gate: bf16 MFMA GEMM H=[xWg | xWn], async LDS staging + xor-swizzle.
__global__ __launch_bounds__(256) void gate_kernel(const float* __restrict__ x,
                                                   const unsigned short* __restrict__ xbf,
                                                   int use_xbf,
                                                   const unsigned short* __restrict__ wgnb,
                                                   const float* __restrict__ nvec,
                                                   int4* __restrict__ records,
                                                   int* __restrict__ risky,
                                                   int* __restrict__ ctrl) {
  __shared__ __align__(16) union {
    struct { short Al[128 * 64]; short Bl[64 * 64]; } t;
    float H[128 * 67];
  } sm;
  __shared__ float nvs[32];
  __shared__ int lh[64];
  int tid = threadIdx.x;
  if (tid < 64) lh[tid] = 0;
  if (tid < 32) nvs[tid] = nvec[tid];
  int t0 = blockIdx.x * 128;
  int lane = tid & 63, wid = tid >> 6;
  int wm = wid * 32;  // 2 m-tiles of 16 per wave
  int lm = lane & 15, lk8 = (lane >> 4) * 8;
  int r0 = tid >> 3, kc = tid & 7;
  int kcs = kc ^ (r0 & 7);  // xor-swizzled source chunk
  v4f acc[2][4];
  v4f zero = {0.f, 0.f, 0.f, 0.f};
#pragma unroll
  for (int mi = 0; mi < 2; ++mi)
#pragma unroll
    for (int ni = 0; ni < 4; ++ni) acc[mi][ni] = zero;
  for (int k0 = 0; k0 < 256; k0 += 64) {
    __syncthreads();
    if (use_xbf) {
#pragma unroll
      for (int j = 0; j < 4; ++j)
        GLOAD_LDS16(xbf + ((size_t)(t0 + r0 + 32 * j) * 256 + k0 + kcs * 8),
                    sm.t.Al + (size_t)(256 * j + (tid & 192)) * 8);
#pragma unroll
      for (int j = 0; j < 2; ++j)
        GLOAD_LDS16(wgnb + ((size_t)(r0 + 32 * j) * 256 + k0 + kcs * 8),
                    sm.t.Bl + (size_t)(256 * j + (tid & 192)) * 8);
    } else {
#pragma unroll
      for (int j = 0; j < 4; ++j) {
        const float4* s = (const float4*)(x + ((size_t)(t0 + r0 + 32 * j) * 256 + k0 + kcs * 8));
        float4 a = s[0], b = s[1];
        union { v8bf v; unsigned short u[8]; } p;
        p.u[0] = f2bf(a.x); p.u[1] = f2bf(a.y); p.u[2] = f2bf(a.z); p.u[3] = f2bf(a.w);
        p.u[4] = f2bf(b.x); p.u[5] = f2bf(b.y); p.u[6] = f2bf(b.z); p.u[7] = f2bf(b.w);
        *(v8bf*)(sm.t.Al + (size_t)(tid + 256 * j) * 8) = p.v;
      }
#pragma unroll
      for (int j = 0; j < 2; ++j) {
        uint4 w = *(const uint4*)(wgnb + ((size_t)(r0 + 32 * j) * 256 + k0 + kcs * 8));
        *(uint4*)(sm.t.Bl + (size_t)(tid + 256 * j) * 8) = w;
      }
    }
    __syncthreads();
#pragma unroll
    for (int ks = 0; ks < 64; ks += 32) {
      int c = (ks + lk8) >> 3;
      int cs = c ^ (lm & 7);
      v8bf af[2], bfr[4];
#pragma unroll
      for (int mi = 0; mi < 2; ++mi)
        af[mi] = *(const v8bf*)(sm.t.Al + (size_t)((wm + mi * 16 + lm) * 8 + cs) * 8);
#pragma unroll
      for (int ni = 0; ni < 4; ++ni)
        bfr[ni] = *(const v8bf*)(sm.t.Bl + (size_t)((ni * 16 + lm) * 8 + cs) * 8);
#pragma unroll
      for (int mi = 0; mi < 2; ++mi)
#pragma unroll
        for (int ni = 0; ni < 4; ++ni)
          acc[mi][ni] = __builtin_amdgcn_mfma_f32_16x16x32_bf16(af[mi], bfr[ni], acc[mi][ni], 0, 0, 0);
    }
  }
  __syncthreads();  // Al/Bl dead; reuse as H
  int cg = lane & 15, rg = lane >> 4;
#pragma unroll
  for (int mi = 0; mi < 2; ++mi)
#pragma unroll
    for (int r = 0; r < 4; ++r) {
      int row = wm + mi * 16 + rg * 4 + r;
#pragma unroll
      for (int ni = 0; ni < 4; ++ni) sm.H[row * 67 + ni * 16 + cg] = acc[mi][ni][r];
    }
  __syncthreads();
  if (tid < 128) {
    int t = t0 + tid;
    float v1 = -3e38f, v2 = -3e38f, v3 = -3e38f;
    int i1 = 0, i2 = 0;
#pragma unroll 4
    for (int e = 0; e < 32; ++e) {
      float g = sm.H[tid * 67 + e];
      float n = sm.H[tid * 67 + 32 + e];
      float sp = fmaxf(n, 0.f) + log1pf(expf(-fabsf(n)));
      float he = fmaf(nvs[e], sp, g);
      if (he > v1) { v3 = v2; v2 = v1; i2 = i1; v1 = he; i1 = e; }
      else if (he > v2) { v3 = v2; v2 = he; i2 = e; }
      else if (he > v3) v3 = he;
    }
    float w1v = 1.f / (1.f + expf(v2 - v1));
    float w2v = 1.f / (1.f + expf(v1 - v2));
    records[t] = make_int4(i1, i2, __float_as_int(w1v), __float_as_int(w2v));
    atomicAdd(&lh[i1], 1);
    atomicAdd(&lh[32 + i2], 1);
    if (v2 - v3 < 2e-2f) {
      int p = atomicAdd(&ctrl[C_RISKY], 1);
      risky[p] = t;
    }
  }
  __syncthreads();
  if (tid < 32) atomicAdd(&ctrl[C_HIST1 + tid], lh[tid]);
  else if (tid < 64) atomicAdd(&ctrl[C_HIST2 + (tid - 32)], lh[tid]);
}

// fp64 recompute of gating for risky tokens; patches records + histograms.
__global__ __launch_bounds__(256) void fixup_kernel(const float* __restrict__ x,
                                                    const float* __restrict__ wgn,
                                                    const float* __restrict__ nvec,
                                                    int4* __restrict__ records,
                                                    const int* __restrict__ risky,
                                                    int* __restrict__ ctrl) {
  int cnt = ctrl[C_RISKY];
  int lane = threadIdx.x & 63, wid = threadIdx.x >> 6;
  for (int r = blockIdx.x * 4 + wid; r < cnt; r += gridDim.x * 4) {
    int t = __builtin_amdgcn_readfirstlane(risky[r]);
    const float* xr = x + (size_t)t * 256;
    double a0 = 0.0, a1 = 0.0, a2 = 0.0, a3 = 0.0;
    for (int k = 0; k < 256; k += 4) {
      float4 xv = *(const float4*)(xr + k);
      a0 = fma((double)xv.x, (double)wgn[(k + 0) * 64 + lane], a0);
      a1 = fma((double)xv.y, (double)wgn[(k + 1) * 64 + lane], a1);
      a2 = fma((double)xv.z, (double)wgn[(k + 2) * 64 + lane], a2);
      a3 = fma((double)xv.w, (double)wgn[(k + 3) * 64 + lane], a3);
    }
    double acc = (a0 + a1) + (a2 + a3);
    double sv = __shfl(acc, lane + 32);
    double H;
    if (lane < 32) {
      double sp = fmax(sv, 0.0) + log1p(exp(-fabs(sv)));
      H = acc + (double)nvec[lane] * sp;
    } else
      H = -1e300;
    double v = H; int idx = lane;
#pragma unroll
    for (int off = 32; off >= 1; off >>= 1) {
      double ov = __shfl_xor(v, off); int oi = __shfl_xor(idx, off);
      if (ov > v || (ov == v && oi < idx)) { v = ov; idx = oi; }
    }
    int i1 = idx; double v1 = v;
    v = (lane == i1) ? -1e300 : H; idx = lane;
#pragma unroll
    for (int off = 32; off >= 1; off >>= 1) {
      double ov = __shfl_xor(v, off); int oi = __shfl_xor(idx, off);
      if (ov > v || (ov == v && oi < idx)) { v = ov; idx = oi; }
    }
    int i2 = idx; double v2 = v;
    if (lane == 0) {
      float w1v = (float)(1.0 / (1.0 + exp(v2 - v1)));
      float w2v = (float)(1.0 / (1.0 + exp(v1 - v2)));
      int4 old = records[t];
      if (old.x != i1) { atomicSub(&ctrl[C_HIST1 + old.x], 1); atomicAdd(&ctrl[C_HIST1 + i1], 1); }
      if (old.y != i2) { atomicSub(&ctrl[C_HIST2 + old.y], 1); atomicAdd(&ctrl[C_HIST2 + i2], 1); }
      records[t] = make_int4(i1, i2, __float_as_int(w1v), __float_as_int(w2v));
    }
  }
}

// Segment offsets + per-tile work tables (BM=128 tiles per expert segment).
__global__ __launch_bounds__(64) void scan_kernel(int* __restrict__ ctrl,
                                                  int4* __restrict__ table1,
                                                  int4* __restrict__ table2) {
  __shared__ int so1[32], so2[32], tp1[32], tp2[32];
  int tid = threadIdx.x;
  if (tid == 0) {
    int o = 0, tp = 0;
    for (int e = 0; e < 32; ++e) {
      so1[e] = o; tp1[e] = tp;
      int c = ctrl[C_HIST1 + e];
      o += c; tp += (c + 127) >> 7;
    }
    ctrl[C_TC1] = tp;
    o = 0; tp = 0;
    for (int e = 0; e < 32; ++e) {
      so2[e] = o; tp2[e] = tp;
      int c = ctrl[C_HIST2 + e];
      o += c; tp += (c + 127) >> 7;
    }
    ctrl[C_TC2] = tp;
  }
  __syncthreads();
  if (tid < 32) {
    int e = tid;
    ctrl[C_CUR1 + e] = so1[e];
    int c = ctrl[C_HIST1 + e];
    int nt = (c + 127) >> 7;
    for (int m = 0; m < nt; ++m)
      table1[tp1[e] + m] = make_int4(e, so1[e] + m * 128, min(128, c - m * 128), 0);
  } else if (tid < 64) {
    int e = tid - 32;
    ctrl[C_CUR2 + e] = so2[e];
    int c = ctrl[C_HIST2 + e];
    int nt = (c + 127) >> 7;
    for (int m = 0; m < nt; ++m)
      table2[tp2[e] + m] = make_int4(e, so2[e] + m * 128, min(128, c - m * 128), 0);
  }
}

// Bucket tokens by expert; also records tpos2[t] = slot of t in perm2.
__global__ __launch_bounds__(256) void scatter_kernel(const int4* __restrict__ records,
                                                      int* __restrict__ ctrl,
                                                      int* __restrict__ perm1, float* __restrict__ pw1,
                                                      int* __restrict__ perm2, float* __restrict__ pw2,
                                                      int* __restrict__ tpos2) {
  __shared__ int lh1[32], lh2[32], b1[32], b2[32];
  int tid = threadIdx.x;
  if (tid < 32) { lh1[tid] = 0; lh2[tid] = 0; }
  __syncthreads();
  int t = blockIdx.x * 256 + tid;
  int4 rec = records[t];
  int r1 = atomicAdd(&lh1[rec.x], 1);
  int r2 = atomicAdd(&lh2[rec.y], 1);
  __syncthreads();
  if (tid < 32) {
    b1[tid] = atomicAdd(&ctrl[C_CUR1 + tid], lh1[tid]);
    b2[tid] = atomicAdd(&ctrl[C_CUR2 + tid], lh2[tid]);
  }
  __syncthreads();
  int s1 = b1[rec.x] + r1; perm1[s1] = t; pw1[s1] = __int_as_float(rec.z);
  int s2 = b2[rec.y] + r2; perm2[s2] = t; pw2[s2] = __int_as_float(rec.w);
  tpos2[t] = s2;
}

// Grouped GEMM, BM=128 BN=128 BK=128 (2 K-iters), 64KB LDS, async staging.
// mode 0: write y1[slot] (bf16, slot-contiguous)         [expert-2 pass]
// mode 1: out[tok] = acc*w + bias + y1[tpos2[tok]]       [expert-1 pass, fused combine]
// mode 2: out[tok] = acc*w + bias                        [fallback pass 1]
// mode 3: out[tok] += acc*w + bias                       [fallback pass 2]
__global__ __launch_bounds__(256) void expert_kernel(const float* __restrict__ x,
                                                     const unsigned short* __restrict__ xbf,
                                                     int use_xbf,
                                                     const unsigned short* __restrict__ WeT,
                                                     const float* __restrict__ be,
                                                     const int* __restrict__ perm,
                                                     const float* __restrict__ pw,
                                                     const int* __restrict__ tpos2,
                                                     unsigned short* __restrict__ y1,
                                                     const int4* __restrict__ table,
                                                     const int* __restrict__ tcp,
                                                     float* __restrict__ out,
                                                     int mode) {
  int nt = *tcp;
  if (blockIdx.x >= nt) return;
  int4 ent = table[blockIdx.x];
  int e = ent.x, sbase = ent.y, rows = ent.z;
  int n0 = blockIdx.y * 128;
  __shared__ __align__(16) short Al[128 * 128];  // [row][k], 256B rows, xor-swizzled chunks
  __shared__ __align__(16) short Bl[128 * 128];
  int tid = threadIdx.x;
  int lane = tid & 63, wid = tid >> 6;
  int wm = (wid & 1) * 64, wn = (wid >> 1) * 64;
  int lm = lane & 15, lk8 = (lane >> 4) * 8;
  int hb = lane >> 4;   // row-within-quad for staging (4 rows per 1KB wave-instr)
  int cl = lane & 15;   // chunk-slot within row (16 chunks of 16B per 128-k window)
  // rows this thread stages: w*32 + 4i + hb, i=0..7
  int tokA[8];
#pragma unroll
  for (int i = 0; i < 8; ++i)
    tokA[i] = perm[sbase + min(wid * 32 + 4 * i + hb, rows - 1)];
  v4f acc[4][4];
  v4f zero = {0.f, 0.f, 0.f, 0.f};
#pragma unroll
  for (int mi = 0; mi < 4; ++mi)
#pragma unroll
    for (int ni = 0; ni < 4; ++ni) acc[mi][ni] = zero;
  for (int k0 = 0; k0 < 256; k0 += 128) {
    __syncthreads();
    if (use_xbf) {
#pragma unroll
      for (int i = 0; i < 8; ++i) {
        int row = wid * 32 + 4 * i + hb;
        int csrc = cl ^ (row & 7);
        GLOAD_LDS16(xbf + ((size_t)tokA[i] * 256 + k0 + csrc * 8),
                    Al + (size_t)(wid * 32 + 4 * i) * 128);
      }
#pragma unroll
      for (int i = 0; i < 8; ++i) {
        int row = wid * 32 + 4 * i + hb;
        int csrc = cl ^ (row & 7);
        GLOAD_LDS16(WeT + (((size_t)e * 256 + n0 + row) * 256 + k0 + csrc * 8),
                    Bl + (size_t)(wid * 32 + 4 * i) * 128);
      }
    } else {
      // fallback: VGPR-stage A from fp32 x (convert inline); B via VGPR too
#pragma unroll
      for (int j = 0; j < 8; ++j) {
        int idx = tid + 256 * j;  // 2048 chunks
        int row = idx >> 4, cslot = idx & 15;
        int csrc = cslot ^ (row & 7);
        int tokr = perm[sbase + min(row, rows - 1)];
        const float4* s = (const float4*)(x + ((size_t)tokr * 256 + k0 + csrc * 8));
        float4 a = s[0], b = s[1];
        union { v8bf v; unsigned short u[8]; } p;
        p.u[0] = f2bf(a.x); p.u[1] = f2bf(a.y); p.u[2] = f2bf(a.z); p.u[3] = f2bf(a.w);
        p.u[4] = f2bf(b.x); p.u[5] = f2bf(b.y); p.u[6] = f2bf(b.z); p.u[7] = f2bf(b.w);
        *(v8bf*)(Al + (size_t)(row * 16 + cslot) * 8) = p.v;
        uint4 w = *(const uint4*)(WeT + (((size_t)e * 256 + n0 + row) * 256 + k0 + csrc * 8));
        *(uint4*)(Bl + (size_t)(row * 16 + cslot) * 8) = w;
      }
    }
    __syncthreads();
#pragma unroll
    for (int ks = 0; ks < 128; ks += 32) {
      int c = (ks + lk8) >> 3;
      int cs = c ^ (lm & 7);
      v8bf af[4], bfr[4];
#pragma unroll
      for (int mi = 0; mi < 4; ++mi)
        af[mi] = *(const v8bf*)(Al + (size_t)((wm + mi * 16 + lm) * 16 + cs) * 8);
#pragma unroll
      for (int ni = 0; ni < 4; ++ni)
        bfr[ni] = *(const v8bf*)(Bl + (size_t)((wn + ni * 16 + lm) * 16 + cs) * 8);
#pragma unroll
      for (int mi = 0; mi < 4; ++mi)
#pragma unroll
        for (int ni = 0; ni < 4; ++ni)
          acc[mi][ni] = __builtin_amdgcn_mfma_f32_16x16x32_bf16(af[mi], bfr[ni], acc[mi][ni], 0, 0, 0);
    }
  }
  // epilogue: C/D layout col=lane&15, row=(lane>>4)*4+reg
  int cg = lane & 15, rg = lane >> 4;
#pragma unroll
  for (int mi = 0; mi < 4; ++mi) {
#pragma unroll
    for (int r = 0; r < 4; ++r) {
      int srow = wm + mi * 16 + rg * 4 + r;
      if (srow < rows) {
        int slot = sbase + srow;
        float w = pw[slot];
        if (mode == 0) {
          unsigned short* yrow = y1 + (size_t)slot * 256 + n0 + wn;
#pragma unroll
          for (int ni = 0; ni < 4; ++ni) {
            int c = ni * 16 + cg;
            float v = acc[mi][ni][r] * w + w * be[e * 256 + n0 + wn + c];
            yrow[c] = f2bf(v);
          }
        } else if (mode == 1) {
          int tokr = perm[slot];
          int s2 = tpos2[tokr];
          const unsigned short* yr = y1 + (size_t)s2 * 256 + n0 + wn;
          float* orow = out + (size_t)tokr * 256 + n0 + wn;
#pragma unroll
          for (int ni = 0; ni < 4; ++ni) {
            int c = ni * 16 + cg;
            float v = acc[mi][ni][r] * w + w * be[e * 256 + n0 + wn + c];
            orow[c] = v + bf2f(yr[c]);
          }
        } else {
          int tokr = perm[slot];
          float* orow = out + (size_t)tokr * 256 + n0 + wn;
#pragma unroll
          for (int ni = 0; ni < 4; ++ni) {
            int c = ni * 16 + cg;
            float v = acc[mi][ni][r] * w + w * be[e * 256 + n0 + wn + c];
            if (mode == 3) orow[c] += v;
            else orow[c] = v;
          }
        }
      }
    }
  }
}

extern "C" void kernel_launch(void* const* d_in, const int* in_sizes, int n_in,
                              void* d_out, int out_size, void* d_ws, size_t ws_size,
                              hipStream_t stream) {
  const float* x = (const float*)d_in[0];
  const float* Wg = (const float*)d_in[1];
  const float* Wn = (const float*)d_in[2];
  const float* We = (const float*)d_in[3];
  const float* be = (const float*)d_in[4];
  const float* nvec = (const float*)d_in[5];
  float* out = (float*)d_out;
  char* ws = (char*)d_ws;
  size_t off = 0;
  auto alloc = [&](size_t bytes) -> void* {
    void* p = ws + off;
    off = (off + bytes + 255) & ~(size_t)255;
    return p;
  };
  int* ctrl = (int*)alloc(4096);
  int4* records = (int4*)alloc((size_t)NT * 16);
  int* risky = (int*)alloc((size_t)NT * 4);
  int* perm1 = (int*)alloc((size_t)NT * 4);
  float* pw1 = (float*)alloc((size_t)NT * 4);
  int* perm2 = (int*)alloc((size_t)NT * 4);
  float* pw2 = (float*)alloc((size_t)NT * 4);
  int* tpos2 = (int*)alloc((size_t)NT * 4);
  int4* table1 = (int4*)alloc(1024 * 16);
  int4* table2 = (int4*)alloc(1024 * 16);
  float* wgn = (float*)alloc(256 * 64 * 4);
  unsigned short* wgnb = (unsigned short*)alloc(64 * 256 * 2);
  unsigned short* WeT = (unsigned short*)alloc((size_t)NE * 256 * 256 * 2);
  unsigned short* xbf = nullptr;
  int use_xbf = 0;
  if (off + (size_t)NT * 256 * 2 <= ws_size) {
    xbf = (unsigned short*)alloc((size_t)NT * 256 * 2);
    use_xbf = 1;
  }
  unsigned short* y1 = nullptr;
  int use_y1 = 0;
  if (off + (size_t)NT * 256 * 2 <= ws_size) {
    y1 = (unsigned short*)alloc((size_t)NT * 256 * 2);
    use_y1 = 1;
  }

  hipMemsetAsync(ctrl, 0, 4096, stream);
  prep_w<<<64, 256, 0, stream>>>(Wg, Wn, wgn, wgnb);
  prep_wet<<<dim3(32, 64), 256, 0, stream>>>(We, WeT);
  if (use_xbf) convert_kernel<<<NT * DM / 8 / 256, 256, 0, stream>>>(x, xbf);
  gate_kernel<<<NT / 128, 256, 0, stream>>>(x, xbf, use_xbf, wgnb, nvec, records, risky, ctrl);
  fixup_kernel<<<256, 256, 0, stream>>>(x, wgn, nvec, records, risky, ctrl);
  scan_kernel<<<1, 64, 0, stream>>>(ctrl, table1, table2);
  scatter_kernel<<<NT / 256, 256, 0, stream>>>(records, ctrl, perm1, pw1, perm2, pw2, tpos2);
  if (use_y1) {
    // pass A: expert-2 list -> y1 (slot-contiguous bf16)
    expert_kernel<<<dim3(544, 2), 256, 0, stream>>>(x, xbf, use_xbf, WeT, be, perm2, pw2,
                                                    tpos2, y1, table2, ctrl + C_TC2, out, 0);
    // pass B: expert-1 list -> out = acc*w1 + y1[tpos2[tok]]
    expert_kernel<<<dim3(544, 2), 256, 0, stream>>>(x, xbf, use_xbf, WeT, be, perm1, pw1,
                                                    tpos2, y1, table1, ctrl + C_TC1, out, 1);
  } else {
    expert_kernel<<<dim3(544, 2), 256, 0, stream>>>(x, xbf, use_xbf, WeT, be, perm1, pw1,
                                                    tpos2, y1, table1, ctrl + C_TC1, out, 2);
    expert_kernel<<<dim3(544, 2), 256, 0, stream>>>(x, xbf, use_xbf, WeT, be, perm2, pw2,
                                                    tpos2, y1, table2, ctrl + C_TC2, out, 3);
  }
}